// Round 16
// baseline (49.173 us; speedup 1.0000x reference)
//
#include <hip/hip_runtime.h>

#define T_STEPS 128

// native clang vectors
typedef float    vfloat4 __attribute__((ext_vector_type(4)));
typedef _Float16 h4      __attribute__((ext_vector_type(4)));

// ---------------------------------------------------------------------------
// Fused prep: [0,totC) builds uint4 spike masks mask[c] = {bits t=0..31,
// 32..63, 64..95, 96..127} (16B contiguous per column -> ONE gather in
// main); [totC,..) CSR starts via adjacent-difference fill on sorted rows.
// ---------------------------------------------------------------------------
__global__ __launch_bounds__(256) void prep_kernel(
    const float* __restrict__ lgn_spikes, int lgn_C, uint4* __restrict__ lgn_mask,
    const float* __restrict__ bkg_spikes, int bkg_C, uint4* __restrict__ bkg_mask,
    const int* __restrict__ lgn_rows, int nnz_l, int* __restrict__ lgn_start,
    const int* __restrict__ bkg_rows, int nnz_b, int* __restrict__ bkg_start,
    int R)
{
    int gid = blockIdx.x * 256 + threadIdx.x;
    int totC = lgn_C + bkg_C;

    if (gid < totC) {
        const float* sp; uint4* mask; int C, cc;
        if (gid < lgn_C) { sp = lgn_spikes; mask = lgn_mask; C = lgn_C; cc = gid; }
        else             { sp = bkg_spikes; mask = bkg_mask; C = bkg_C; cc = gid - lgn_C; }
        unsigned int m0 = 0u, m1 = 0u, m2 = 0u, m3 = 0u;
        #pragma unroll 4
        for (int t = 0; t < 32; ++t) {
            if (sp[(size_t)(t)       * C + cc] != 0.0f) m0 |= (1u << t);
            if (sp[(size_t)(t +  32) * C + cc] != 0.0f) m1 |= (1u << t);
            if (sp[(size_t)(t +  64) * C + cc] != 0.0f) m2 |= (1u << t);
            if (sp[(size_t)(t +  96) * C + cc] != 0.0f) m3 |= (1u << t);
        }
        mask[cc] = make_uint4(m0, m1, m2, m3);
        return;
    }

    int i = gid - totC;
    const int* rows; int nnz; int* start;
    if (i < nnz_l) { rows = lgn_rows; nnz = nnz_l; start = lgn_start; }
    else {
        i -= nnz_l;
        if (i >= nnz_b) return;
        rows = bkg_rows; nnz = nnz_b; start = bkg_start;
    }
    int cur  = rows[i];
    int prev = (i == 0) ? -1 : rows[i - 1];
    for (int rr = prev + 1; rr <= cur; ++rr) start[rr] = i;
    if (i == nnz - 1)
        for (int rr = cur + 1; rr <= R; ++rr) start[rr] = nnz;
}

// ---------------------------------------------------------------------------
// Main: thread = row r, ALL 128 timesteps in packed f16 (h4 acc[32] = 64
// VGPRs; launch_bounds(256,4) -> 128 budget, no spill). ONE visit per
// synapse (was 2): 1 col + 1 w + ONE uint4 (16B) mask gather; 32 nibble
// b64 LUT reads (16-entry 4xf16, disjoint bank pairs -> conflict-free) +
// 32 v_pk_fma_f16. Per-synapse overhead paid once, and the 32-read body
// gives the 2-deep prefetch more work to hide the col->mask chain under.
// 782 blocks all co-resident at 4 blocks/CU (no tail). Stores staged via
// LDS tile -> vfloat4 nontemporal, 8 passes of 16 planes. Output written
// exactly once.
// ---------------------------------------------------------------------------
__global__ __launch_bounds__(256, 4) void sparse_lut_kernel(
    const int* __restrict__ lgn_cols, const float* __restrict__ lgn_w,
    const int* __restrict__ lgn_start,
    const int* __restrict__ bkg_cols, const float* __restrict__ bkg_w,
    const int* __restrict__ bkg_start,
    const uint4* __restrict__ lgn_mask,   // [lgn_C]
    const uint4* __restrict__ bkg_mask,   // [bkg_C]
    int lgn_C, int bkg_C, int R,
    float* __restrict__ out)
{
    __shared__ h4 lut[16];                // 16 x 8B, disjoint bank pairs
    __shared__ float tile[16 * 260];
    const int tid = threadIdx.x;
    if (tid < 16)
        lut[tid] = (h4){ (_Float16)(tid & 1), (_Float16)((tid >> 1) & 1),
                         (_Float16)((tid >> 2) & 1), (_Float16)((tid >> 3) & 1) };

    const int r0 = blockIdx.x * 256;
    const int r  = r0 + tid;

    h4 acc[32];                           // 128 timesteps in f16
    #pragma unroll
    for (int k = 0; k < 32; ++k) acc[k] = (h4)0;

    int l0 = 0, l1 = 0, g0 = 0, g1 = 0;
    if (r < R) {
        l0 = lgn_start[r]; l1 = lgn_start[r + 1];
        g0 = bkg_start[r]; g1 = bkg_start[r + 1];
    }
    __syncthreads();   // lut ready

    // one 32-bit mask word -> 8 nibble LUT reads (b64) + 8 pk_fma4
    #define ACC_WORD(mw, base, w4)                                           \
        _Pragma("unroll")                                                    \
        for (int nb = 0; nb < 8; ++nb) {                                     \
            h4 s = lut[((mw) >> (nb * 4)) & 15u];                            \
            acc[(base) + nb] = __builtin_elementwise_fma(s, w4, acc[(base) + nb]); \
        }

    // 2-deep col/w prefetch, 1-deep mask prefetch
    #define ACC_RANGE(cols_a, w_a, mask_p, I0, I1)                           \
    {                                                                        \
        int i0 = (I0), i1 = (I1);                                            \
        if (i0 < i1) {                                                       \
            float w0 = w_a[i0];                                              \
            int   c1 = 0; float w1 = 0.0f;                                   \
            if (i0 + 1 < i1) { c1 = cols_a[i0 + 1]; w1 = w_a[i0 + 1]; }      \
            uint4 m0 = mask_p[cols_a[i0]];                                   \
            for (int i = i0; i < i1; ++i) {                                  \
                uint4 m1v = make_uint4(0u, 0u, 0u, 0u);                      \
                if (i + 1 < i1) m1v = mask_p[c1];                            \
                int c2 = 0; float w2 = 0.0f;                                 \
                if (i + 2 < i1) { c2 = cols_a[i + 2]; w2 = w_a[i + 2]; }     \
                _Float16 wh = (_Float16)w0;                                  \
                h4 w4 = (h4){ wh, wh, wh, wh };                              \
                ACC_WORD(m0.x, 0,  w4)                                       \
                ACC_WORD(m0.y, 8,  w4)                                       \
                ACC_WORD(m0.z, 16, w4)                                       \
                ACC_WORD(m0.w, 24, w4)                                       \
                m0 = m1v; w0 = w1; c1 = c2; w1 = w2;                         \
            }                                                                \
        }                                                                    \
    }

    ACC_RANGE(lgn_cols, lgn_w, lgn_mask, l0, l1)
    ACC_RANGE(bkg_cols, bkg_w, bkg_mask, g0, g1)
    #undef ACC_RANGE
    #undef ACC_WORD

    // staged store: 8 passes of 16 planes; f16 -> f32 on stage write
    const int wid  = tid >> 6;
    const int lane = tid & 63;
    #pragma unroll
    for (int pass = 0; pass < 8; ++pass) {
        #pragma unroll
        for (int p = 0; p < 16; ++p) {
            const int tl = pass * 16 + p;         // 0..127, compile-time
            tile[p * 260 + tid] = (float)acc[tl >> 2][tl & 3];
        }
        __syncthreads();
        #pragma unroll
        for (int pp = 0; pp < 4; ++pp) {
            int p  = wid * 4 + pp;
            int rr = r0 + 4 * lane;
            vfloat4 v = *(const vfloat4*)&tile[p * 260 + 4 * lane];
            int t = pass * 16 + p;
            float* dst = &out[(size_t)t * R + rr];
            if (rr + 3 < R) {
                __builtin_nontemporal_store(v, (vfloat4*)dst);
            } else {
                if (rr     < R) __builtin_nontemporal_store(v.x, dst);
                if (rr + 1 < R) __builtin_nontemporal_store(v.y, dst + 1);
                if (rr + 2 < R) __builtin_nontemporal_store(v.z, dst + 2);
            }
        }
        __syncthreads();
    }
}

// ---------------------------------------------------------------------------
// Fallback (small ws): inline binary search + direct float gathers.
// ---------------------------------------------------------------------------
__global__ __launch_bounds__(256) void sparse_fallback_kernel(
    const int* __restrict__ lgn_rows, const int* __restrict__ lgn_cols,
    const float* __restrict__ lgn_w, int nnz_l,
    const int* __restrict__ bkg_rows, const int* __restrict__ bkg_cols,
    const float* __restrict__ bkg_w, int nnz_b,
    const float* __restrict__ lgn_spikes, const float* __restrict__ bkg_spikes,
    int lgn_C, int bkg_C, int R,
    float* __restrict__ out)
{
    int r = blockIdx.x * 256 + threadIdx.x;
    int q = blockIdx.y;
    if (r >= R) return;

    float acc[32];
    #pragma unroll
    for (int t = 0; t < 32; ++t) acc[t] = 0.0f;

    {
        int lo = 0, hi = nnz_l;
        while (lo < hi) { int mid = (lo + hi) >> 1; if (lgn_rows[mid] < r) lo = mid + 1; else hi = mid; }
        for (int i = lo; i < nnz_l && lgn_rows[i] == r; ++i) {
            float wt = lgn_w[i];
            const float* sp = lgn_spikes + (size_t)(q * 32) * lgn_C + lgn_cols[i];
            #pragma unroll
            for (int t = 0; t < 32; ++t)
                acc[t] = fmaf(wt, sp[(size_t)t * lgn_C], acc[t]);
        }
    }
    {
        int lo = 0, hi = nnz_b;
        while (lo < hi) { int mid = (lo + hi) >> 1; if (bkg_rows[mid] < r) lo = mid + 1; else hi = mid; }
        for (int i = lo; i < nnz_b && bkg_rows[i] == r; ++i) {
            float wt = bkg_w[i];
            const float* sp = bkg_spikes + (size_t)(q * 32) * bkg_C + bkg_cols[i];
            #pragma unroll
            for (int t = 0; t < 32; ++t)
                acc[t] = fmaf(wt, sp[(size_t)t * bkg_C], acc[t]);
        }
    }

    float* op = out + (size_t)(q * 32) * R + r;
    #pragma unroll
    for (int t = 0; t < 32; ++t) op[(size_t)t * R] = acc[t];
}

extern "C" void kernel_launch(void* const* d_in, const int* in_sizes, int n_in,
                              void* d_out, int out_size, void* d_ws, size_t ws_size,
                              hipStream_t stream)
{
    const float* lgn_spikes = (const float*)d_in[0];
    const float* bkg_spikes = (const float*)d_in[1];
    const int*   lgn_rows   = (const int*)d_in[2];
    const int*   lgn_cols   = (const int*)d_in[3];
    const float* lgn_w      = (const float*)d_in[4];
    const int*   bkg_rows   = (const int*)d_in[5];
    const int*   bkg_cols   = (const int*)d_in[6];
    const float* bkg_w      = (const float*)d_in[7];
    float* out = (float*)d_out;

    const int nnz_l = in_sizes[2];
    const int nnz_b = in_sizes[5];
    const int lgn_C = in_sizes[0] / T_STEPS;   // 17400
    const int bkg_C = in_sizes[1] / T_STEPS;   // 100
    const int R     = out_size / T_STEPS;      // 200000
    const int NBLK  = (R + 255) / 256;         // 782

    // ws layout (16B-aligned sections)
    size_t off = 0;
    auto take = [&](size_t bytes) { size_t o = off; off = (off + bytes + 15) & ~(size_t)15; return o; };
    size_t o_lgn_start = take((size_t)(R + 1) * sizeof(int));
    size_t o_bkg_start = take((size_t)(R + 1) * sizeof(int));
    size_t o_lgn_mask  = take((size_t)lgn_C * sizeof(uint4));
    size_t o_bkg_mask  = take((size_t)bkg_C * sizeof(uint4));
    size_t need = off;

    dim3 blk(256);

    if (ws_size >= need) {
        char* ws = (char*)d_ws;
        int* lgn_start = (int*)(ws + o_lgn_start);
        int* bkg_start = (int*)(ws + o_bkg_start);
        uint4* lgn_mask = (uint4*)(ws + o_lgn_mask);
        uint4* bkg_mask = (uint4*)(ws + o_bkg_mask);

        int prep_threads = (lgn_C + bkg_C) + nnz_l + nnz_b;
        prep_kernel<<<(prep_threads + 255) / 256, blk, 0, stream>>>(
            lgn_spikes, lgn_C, lgn_mask, bkg_spikes, bkg_C, bkg_mask,
            lgn_rows, nnz_l, lgn_start, bkg_rows, nnz_b, bkg_start, R);

        sparse_lut_kernel<<<NBLK, blk, 0, stream>>>(
            lgn_cols, lgn_w, lgn_start,
            bkg_cols, bkg_w, bkg_start,
            lgn_mask, bkg_mask,
            lgn_C, bkg_C, R, out);
    } else {
        dim3 grid_main((R + 255) / 256, 4);
        sparse_fallback_kernel<<<grid_main, blk, 0, stream>>>(
            lgn_rows, lgn_cols, lgn_w, nnz_l,
            bkg_rows, bkg_cols, bkg_w, nnz_b,
            lgn_spikes, bkg_spikes,
            lgn_C, bkg_C, R, out);
    }
}

// Round 17
// 47.193 us; speedup vs baseline: 1.0419x; 1.0419x over previous
//
#include <hip/hip_runtime.h>

#define T_STEPS 128

// native clang vectors
typedef float    vfloat4 __attribute__((ext_vector_type(4)));
typedef _Float16 h4      __attribute__((ext_vector_type(4)));

// ---------------------------------------------------------------------------
// Fused prep: masks in PAIRED layout mask[q*C+c] = uint2{bits t=q*64+0..31,
// bits 32..63}; CSR starts via adjacent-difference fill on the sorted rows.
// ---------------------------------------------------------------------------
__global__ __launch_bounds__(256) void prep_kernel(
    const float* __restrict__ lgn_spikes, int lgn_C, uint2* __restrict__ lgn_mask,
    const float* __restrict__ bkg_spikes, int bkg_C, uint2* __restrict__ bkg_mask,
    const int* __restrict__ lgn_rows, int nnz_l, int* __restrict__ lgn_start,
    const int* __restrict__ bkg_rows, int nnz_b, int* __restrict__ bkg_start,
    int R)
{
    int gid = blockIdx.x * 256 + threadIdx.x;
    int totC = lgn_C + bkg_C;

    if (gid < totC) {
        const float* sp; uint2* mask; int C, cc;
        if (gid < lgn_C) { sp = lgn_spikes; mask = lgn_mask; C = lgn_C; cc = gid; }
        else             { sp = bkg_spikes; mask = bkg_mask; C = bkg_C; cc = gid - lgn_C; }
        unsigned int m0 = 0u, m1 = 0u, m2 = 0u, m3 = 0u;
        #pragma unroll 4
        for (int t = 0; t < 32; ++t) {
            if (sp[(size_t)(t)       * C + cc] != 0.0f) m0 |= (1u << t);
            if (sp[(size_t)(t +  32) * C + cc] != 0.0f) m1 |= (1u << t);
            if (sp[(size_t)(t +  64) * C + cc] != 0.0f) m2 |= (1u << t);
            if (sp[(size_t)(t +  96) * C + cc] != 0.0f) m3 |= (1u << t);
        }
        mask[(size_t)0 * C + cc] = make_uint2(m0, m1);   // half 0: t in [0,64)
        mask[(size_t)1 * C + cc] = make_uint2(m2, m3);   // half 1: t in [64,128)
        return;
    }

    int i = gid - totC;
    const int* rows; int nnz; int* start;
    if (i < nnz_l) { rows = lgn_rows; nnz = nnz_l; start = lgn_start; }
    else {
        i -= nnz_l;
        if (i >= nnz_b) return;
        rows = bkg_rows; nnz = nnz_b; start = bkg_start;
    }
    int cur  = rows[i];
    int prev = (i == 0) ? -1 : rows[i - 1];
    for (int rr = prev + 1; rr <= cur; ++rr) start[rr] = i;
    if (i == nnz - 1)
        for (int rr = cur + 1; rr <= R; ++rr) start[rr] = nnz;
}

// ---------------------------------------------------------------------------
// Main (best measured, R15): thread = (row r, t-HALF q). 16-entry LUT of
// 4xf16 selectors (8B entries -> ds_read_b64; entry n on banks {2n,2n+1}:
// the 16 entries tile all 32 banks in disjoint pairs -> never conflict,
// same entry broadcasts). Accumulate packed f16 (v_pk_fma_f16): acc = 16 x
// h4. Selector {0,1} exact in f16; wt quantization + ~7 adds => ~1e-3 error
// vs 1.71e-2 threshold. 2-deep col/w + 1-deep mask pipeline. LDS-staged
// vfloat4 nontemporal stores (1KB/wave-instr). Output written exactly once.
// ---------------------------------------------------------------------------
__global__ __launch_bounds__(256, 5) void sparse_lut_kernel(
    const int* __restrict__ lgn_cols, const float* __restrict__ lgn_w,
    const int* __restrict__ lgn_start,
    const int* __restrict__ bkg_cols, const float* __restrict__ bkg_w,
    const int* __restrict__ bkg_start,
    const uint2* __restrict__ lgn_mask,   // [2][lgn_C]
    const uint2* __restrict__ bkg_mask,   // [2][bkg_C]
    int lgn_C, int bkg_C, int R,
    float* __restrict__ out)
{
    __shared__ h4 lut[16];                // 16 x 8B, disjoint bank pairs
    __shared__ float tile[16 * 260];
    const int tid = threadIdx.x;
    if (tid < 16)
        lut[tid] = (h4){ (_Float16)(tid & 1), (_Float16)((tid >> 1) & 1),
                         (_Float16)((tid >> 2) & 1), (_Float16)((tid >> 3) & 1) };

    const int r0 = blockIdx.x * 256;
    const int r  = r0 + tid;
    const int q  = blockIdx.y;            // t-half: 0 or 1

    h4 acc[16];                           // 64 timesteps in f16
    #pragma unroll
    for (int k = 0; k < 16; ++k) acc[k] = (h4)0;

    const uint2* lm = lgn_mask + (size_t)q * lgn_C;
    const uint2* bm = bkg_mask + (size_t)q * bkg_C;

    int l0 = 0, l1 = 0, g0 = 0, g1 = 0;
    if (r < R) {
        l0 = lgn_start[r]; l1 = lgn_start[r + 1];
        g0 = bkg_start[r]; g1 = bkg_start[r + 1];
    }
    __syncthreads();   // lut ready

    // one 32-bit mask word -> 8 nibble LUT reads (b64) + 16 pk_fma
    #define ACC_WORD(mw, base, w4)                                           \
        _Pragma("unroll")                                                    \
        for (int nb = 0; nb < 8; ++nb) {                                     \
            h4 s = lut[((mw) >> (nb * 4)) & 15u];                            \
            acc[(base) + nb] = __builtin_elementwise_fma(s, w4, acc[(base) + nb]); \
        }

    // 2-deep col/w prefetch, 1-deep mask prefetch
    #define ACC_RANGE(cols_a, w_a, mask_p, I0, I1)                           \
    {                                                                        \
        int i0 = (I0), i1 = (I1);                                            \
        if (i0 < i1) {                                                       \
            float w0 = w_a[i0];                                              \
            int   c1 = 0; float w1 = 0.0f;                                   \
            if (i0 + 1 < i1) { c1 = cols_a[i0 + 1]; w1 = w_a[i0 + 1]; }      \
            uint2 m0 = mask_p[cols_a[i0]];                                   \
            for (int i = i0; i < i1; ++i) {                                  \
                uint2 m1v = make_uint2(0u, 0u);                              \
                if (i + 1 < i1) m1v = mask_p[c1];                            \
                int c2 = 0; float w2 = 0.0f;                                 \
                if (i + 2 < i1) { c2 = cols_a[i + 2]; w2 = w_a[i + 2]; }     \
                _Float16 wh = (_Float16)w0;                                  \
                h4 w4 = (h4){ wh, wh, wh, wh };                              \
                ACC_WORD(m0.x, 0, w4)                                        \
                ACC_WORD(m0.y, 8, w4)                                        \
                m0 = m1v; w0 = w1; c1 = c2; w1 = w2;                         \
            }                                                                \
        }                                                                    \
    }

    ACC_RANGE(lgn_cols, lgn_w, lm, l0, l1)
    ACC_RANGE(bkg_cols, bkg_w, bm, g0, g1)
    #undef ACC_RANGE
    #undef ACC_WORD

    // staged store: 4 passes of 16 planes; f16 -> f32 on stage write
    const int wid  = tid >> 6;
    const int lane = tid & 63;
    #pragma unroll
    for (int pass = 0; pass < 4; ++pass) {
        #pragma unroll
        for (int p = 0; p < 16; ++p) {
            const int tl = pass * 16 + p;         // 0..63, compile-time
            tile[p * 260 + tid] = (float)acc[tl >> 2][tl & 3];
        }
        __syncthreads();
        #pragma unroll
        for (int pp = 0; pp < 4; ++pp) {
            int p  = wid * 4 + pp;
            int rr = r0 + 4 * lane;
            vfloat4 v = *(const vfloat4*)&tile[p * 260 + 4 * lane];
            int t = q * 64 + pass * 16 + p;
            float* dst = &out[(size_t)t * R + rr];
            if (rr + 3 < R) {
                __builtin_nontemporal_store(v, (vfloat4*)dst);
            } else {
                if (rr     < R) __builtin_nontemporal_store(v.x, dst);
                if (rr + 1 < R) __builtin_nontemporal_store(v.y, dst + 1);
                if (rr + 2 < R) __builtin_nontemporal_store(v.z, dst + 2);
            }
        }
        __syncthreads();
    }
}

// ---------------------------------------------------------------------------
// Fallback (small ws): inline binary search + direct float gathers.
// ---------------------------------------------------------------------------
__global__ __launch_bounds__(256) void sparse_fallback_kernel(
    const int* __restrict__ lgn_rows, const int* __restrict__ lgn_cols,
    const float* __restrict__ lgn_w, int nnz_l,
    const int* __restrict__ bkg_rows, const int* __restrict__ bkg_cols,
    const float* __restrict__ bkg_w, int nnz_b,
    const float* __restrict__ lgn_spikes, const float* __restrict__ bkg_spikes,
    int lgn_C, int bkg_C, int R,
    float* __restrict__ out)
{
    int r = blockIdx.x * 256 + threadIdx.x;
    int q = blockIdx.y;
    if (r >= R) return;

    float acc[32];
    #pragma unroll
    for (int t = 0; t < 32; ++t) acc[t] = 0.0f;

    {
        int lo = 0, hi = nnz_l;
        while (lo < hi) { int mid = (lo + hi) >> 1; if (lgn_rows[mid] < r) lo = mid + 1; else hi = mid; }
        for (int i = lo; i < nnz_l && lgn_rows[i] == r; ++i) {
            float wt = lgn_w[i];
            const float* sp = lgn_spikes + (size_t)(q * 32) * lgn_C + lgn_cols[i];
            #pragma unroll
            for (int t = 0; t < 32; ++t)
                acc[t] = fmaf(wt, sp[(size_t)t * lgn_C], acc[t]);
        }
    }
    {
        int lo = 0, hi = nnz_b;
        while (lo < hi) { int mid = (lo + hi) >> 1; if (bkg_rows[mid] < r) lo = mid + 1; else hi = mid; }
        for (int i = lo; i < nnz_b && bkg_rows[i] == r; ++i) {
            float wt = bkg_w[i];
            const float* sp = bkg_spikes + (size_t)(q * 32) * bkg_C + bkg_cols[i];
            #pragma unroll
            for (int t = 0; t < 32; ++t)
                acc[t] = fmaf(wt, sp[(size_t)t * bkg_C], acc[t]);
        }
    }

    float* op = out + (size_t)(q * 32) * R + r;
    #pragma unroll
    for (int t = 0; t < 32; ++t) op[(size_t)t * R] = acc[t];
}

extern "C" void kernel_launch(void* const* d_in, const int* in_sizes, int n_in,
                              void* d_out, int out_size, void* d_ws, size_t ws_size,
                              hipStream_t stream)
{
    const float* lgn_spikes = (const float*)d_in[0];
    const float* bkg_spikes = (const float*)d_in[1];
    const int*   lgn_rows   = (const int*)d_in[2];
    const int*   lgn_cols   = (const int*)d_in[3];
    const float* lgn_w      = (const float*)d_in[4];
    const int*   bkg_rows   = (const int*)d_in[5];
    const int*   bkg_cols   = (const int*)d_in[6];
    const float* bkg_w      = (const float*)d_in[7];
    float* out = (float*)d_out;

    const int nnz_l = in_sizes[2];
    const int nnz_b = in_sizes[5];
    const int lgn_C = in_sizes[0] / T_STEPS;   // 17400
    const int bkg_C = in_sizes[1] / T_STEPS;   // 100
    const int R     = out_size / T_STEPS;      // 200000

    // ws layout (16B-aligned sections)
    size_t off = 0;
    auto take = [&](size_t bytes) { size_t o = off; off = (off + bytes + 15) & ~(size_t)15; return o; };
    size_t o_lgn_start = take((size_t)(R + 1) * sizeof(int));
    size_t o_bkg_start = take((size_t)(R + 1) * sizeof(int));
    size_t o_lgn_mask  = take((size_t)2 * lgn_C * sizeof(uint2));
    size_t o_bkg_mask  = take((size_t)2 * bkg_C * sizeof(uint2));
    size_t need = off;

    dim3 blk(256);

    if (ws_size >= need) {
        char* ws = (char*)d_ws;
        int* lgn_start = (int*)(ws + o_lgn_start);
        int* bkg_start = (int*)(ws + o_bkg_start);
        uint2* lgn_mask = (uint2*)(ws + o_lgn_mask);
        uint2* bkg_mask = (uint2*)(ws + o_bkg_mask);

        int prep_threads = (lgn_C + bkg_C) + nnz_l + nnz_b;
        prep_kernel<<<(prep_threads + 255) / 256, blk, 0, stream>>>(
            lgn_spikes, lgn_C, lgn_mask, bkg_spikes, bkg_C, bkg_mask,
            lgn_rows, nnz_l, lgn_start, bkg_rows, nnz_b, bkg_start, R);

        dim3 grid_main((R + 255) / 256, 2);
        sparse_lut_kernel<<<grid_main, blk, 0, stream>>>(
            lgn_cols, lgn_w, lgn_start,
            bkg_cols, bkg_w, bkg_start,
            lgn_mask, bkg_mask,
            lgn_C, bkg_C, R, out);
    } else {
        dim3 grid_main((R + 255) / 256, 4);
        sparse_fallback_kernel<<<grid_main, blk, 0, stream>>>(
            lgn_rows, lgn_cols, lgn_w, nnz_l,
            bkg_rows, bkg_cols, bkg_w, nnz_b,
            lgn_spikes, bkg_spikes,
            lgn_C, bkg_C, R, out);
    }
}